// Round 12
// baseline (99.463 us; speedup 1.0000x reference)
//
#include <hip/hip_runtime.h>

// Problem constants (fixed by the reference file)
#define NN 8192
#define PPU 33550336u              // P = N(N-1)/2
static const long long PP = (long long)PPU;
#define NBMW 1048448u              // bitmap words (P/32)
#define NBMF 262112u               // bitmap fx4   (P/128)

typedef float __attribute__((ext_vector_type(4))) fx4;      // nontemporal-store-able

// skewed LDS index for M float4 rows
#define MSI(j) ((j) + ((j) >> 3))

// ---------------------------------------------------------------------------
// shared device bodies
// ---------------------------------------------------------------------------
__device__ __forceinline__ void ab_body(
    const float* __restrict__ nodes, const float* __restrict__ W_enc,
    const float* __restrict__ b_enc, const float* __restrict__ W_cls,
    const float* __restrict__ b_cls,
    float2* __restrict__ Axy, float2* __restrict__ Bzw, int bid, int tid)
{
    __shared__ float  wc[1024];        // W_cls [512][2]
    __shared__ float4 msv[288];        // skewed M rows
    __shared__ float  offs[4];

    for (int i = tid; i < 1024; i += 256) wc[i] = W_cls[i];
    __syncthreads();

    {
        const float4* wr  = (const float4*)(W_enc + tid * 256);
        const float4* wa4 = (const float4*)wc;          // A half
        const float4* wb4 = (const float4*)(wc + 512);  // B half
        float a0 = 0.f, a1 = 0.f, a2 = 0.f, a3 = 0.f;
        #pragma unroll 8
        for (int i = 0; i < 64; ++i) {
            const float4 v   = wr[i];
            const float4 A01 = wa4[2*i],   A23 = wa4[2*i+1];
            const float4 B01 = wb4[2*i],   B23 = wb4[2*i+1];
            a0 += v.x*A01.x + v.y*A01.z + v.z*A23.x + v.w*A23.z;
            a1 += v.x*A01.y + v.y*A01.w + v.z*A23.y + v.w*A23.w;
            a2 += v.x*B01.x + v.y*B01.z + v.z*B23.x + v.w*B23.z;
            a3 += v.x*B01.y + v.y*B01.w + v.z*B23.y + v.w*B23.w;
        }
        msv[MSI(tid)] = make_float4(a0, a1, a2, a3);
    }
    if (tid < 4) {
        const int c = tid & 1, base = (tid < 2) ? 0 : 256;
        float o = 0.f;
        for (int j = 0; j < 256; ++j) o += b_enc[j] * wc[(base + j) * 2 + c];
        if (tid < 2) o += b_cls[tid];      // fold b_cls into the A half
        offs[tid] = o;
    }
    __syncthreads();

    const int gid  = bid * 256 + tid;
    const int n    = gid >> 3;             // 0..8191
    const int part = gid & 7;
    float a0 = 0.f, a1 = 0.f, a2 = 0.f, a3 = 0.f;
    const float4* row = (const float4*)(nodes + (long long)n * 256 + part * 32);
    #pragma unroll
    for (int i = 0; i < 8; ++i) {
        const float4 v = row[i];
        const int j = part * 32 + i * 4;
        const float4 m0 = msv[MSI(j+0)];
        const float4 m1 = msv[MSI(j+1)];
        const float4 m2 = msv[MSI(j+2)];
        const float4 m3 = msv[MSI(j+3)];
        a0 += v.x*m0.x + v.y*m1.x + v.z*m2.x + v.w*m3.x;
        a1 += v.x*m0.y + v.y*m1.y + v.z*m2.y + v.w*m3.y;
        a2 += v.x*m0.z + v.y*m1.z + v.z*m2.z + v.w*m3.z;
        a3 += v.x*m0.w + v.y*m1.w + v.z*m2.w + v.w*m3.w;
    }
    #pragma unroll
    for (int d = 1; d < 8; d <<= 1) {
        a0 += __shfl_xor(a0, d);
        a1 += __shfl_xor(a1, d);
        a2 += __shfl_xor(a2, d);
        a3 += __shfl_xor(a3, d);
    }
    if (part == 0) {
        Axy[n] = make_float2(a0 + offs[0], a1 + offs[1]);
        Bzw[n] = make_float2(a2 + offs[2], a3 + offs[3]);
    }
}

// y-fill for segment g (2 pairs -> one fx4 NT store)   [R10's verified body]
__device__ __forceinline__ void y_seg(
    const float2* __restrict__ Axy, const float2* __restrict__ Bzw,
    float* __restrict__ y, unsigned g)
{
    const unsigned p0 = 2u * g;                       // < 2^26
    const unsigned M  = 16383u;
    const unsigned disc = M * M - 8u * p0;            // exact in uint32
    const float sq = sqrtf((float)disc);
    int s = (int)(((float)M - sq) * 0.5f);
    s = s < 0 ? 0 : (s > NN - 2 ? NN - 2 : s);
    unsigned rs = ((unsigned)s * (M - (unsigned)s)) >> 1;
    while (p0 < rs)                           { --s; rs -= (unsigned)(NN - 1 - s); }
    while (p0 >= rs + (unsigned)(NN - 1 - s)) { rs += (unsigned)(NN - 1 - s); ++s; }
    int t = (int)(p0 - rs) + s + 1;

    float2 a  = Axy[s];
    float2 b0 = Bzw[t];
    const float o0 = a.x + b0.x, o1 = a.y + b0.y;
    if (++t == NN) { ++s; t = s + 1; a = Axy[s]; }    // row crossing (rare)
    float2 b1 = Bzw[t];
    fx4 v = {o0, o1, a.x + b1.x, a.y + b1.y};
    __builtin_nontemporal_store(v, (fx4*)(y + 4u * g));
}

// ---------------------------------------------------------------------------
// K1: blocks 0..255 -> ab projections;  blocks 256..1279 -> zero edge bitmap
// ---------------------------------------------------------------------------
__global__ __launch_bounds__(256) void ab_bmzero_kernel(
    const float* __restrict__ nodes, const float* __restrict__ W_enc,
    const float* __restrict__ b_enc, const float* __restrict__ W_cls,
    const float* __restrict__ b_cls,
    float2* __restrict__ Axy, float2* __restrict__ Bzw,
    unsigned* __restrict__ bm)
{
    const int tid = threadIdx.x, bid = blockIdx.x;
    if (bid >= 256) {
        const unsigned f = (unsigned)(bid - 256) * 256u + (unsigned)tid;
        if (f < NBMF) {
            fx4 z = {0.f, 0.f, 0.f, 0.f};
            __builtin_nontemporal_store(z, (fx4*)bm + f);
        }
        return;
    }
    ab_body(nodes, W_enc, b_enc, W_cls, b_cls, Axy, Bzw, bid, tid);
}

// ---------------------------------------------------------------------------
// K2: scatter edges into the bitmap (atomicOr; idempotent for dup edges)
// ---------------------------------------------------------------------------
__global__ __launch_bounds__(256) void scatter_kernel(
    const int* __restrict__ edges, unsigned* __restrict__ bm, int E)
{
    const int g = blockIdx.x * 256 + threadIdx.x;
    if (g >= E) return;
    const int u = edges[g];
    const int v = edges[E + g];
    if (u < v) {
        const unsigned idx = (((unsigned)u * (16383u - (unsigned)u)) >> 1)
                           + (unsigned)(v - u - 1);
        atomicOr(&bm[idx >> 5], 1u << (idx & 31u));
    }
}

// ---------------------------------------------------------------------------
// K3: co-scheduled output fill.  73,719 blocks, 8:1 role interleave:
//   r = bid%9 == 8 -> yt block (#bid/9 of 8191): 4 fx4 NT stores from bitmap
//   else           -> y block  (#(bid/9)*8+r of 65528): R10's 1-store body
// ---------------------------------------------------------------------------
__global__ __launch_bounds__(256) void fill_kernel(
    const float2* __restrict__ Axy, const float2* __restrict__ Bzw,
    const unsigned* __restrict__ bm,
    float* __restrict__ y, float* __restrict__ yt)
{
    const unsigned q = blockIdx.x / 9u, r = blockIdx.x % 9u;
    const int tid = threadIdx.x;

    if (r == 8u) {
        // yt block q: fx4 units base q*1024 + tid + k*256  (16 KB chunk)
        const unsigned base = q * 1024u + (unsigned)tid;
        #pragma unroll
        for (int k = 0; k < 4; ++k) {
            const unsigned f = base + (unsigned)k * 256u;   // fx4 index = nibble index
            const unsigned w = bm[f >> 3];
            const unsigned nib = (w >> ((f & 7u) * 4u)) & 0xFu;
            fx4 v = { (nib & 1u) ? 1.f : 0.f,
                      (nib & 2u) ? 1.f : 0.f,
                      (nib & 4u) ? 1.f : 0.f,
                      (nib & 8u) ? 1.f : 0.f };
            __builtin_nontemporal_store(v, (fx4*)yt + f);
        }
    } else {
        const unsigned yblk = q * 8u + r;                   // 0..65527
        y_seg(Axy, Bzw, y, yblk * 256u + (unsigned)tid);
    }
}

// ---------------------------------------------------------------------------
// Fallback path (ws too small for bitmap): R10's exact kernels
// ---------------------------------------------------------------------------
__global__ __launch_bounds__(256) void ab_zero_kernel(
    const float* __restrict__ nodes, const float* __restrict__ W_enc,
    const float* __restrict__ b_enc, const float* __restrict__ W_cls,
    const float* __restrict__ b_cls,
    float2* __restrict__ Axy, float2* __restrict__ Bzw,
    float* __restrict__ yt)
{
    const int tid = threadIdx.x, bid = blockIdx.x;
    if (bid >= 256) {
        fx4* base = (fx4*)yt + (unsigned)(bid - 256) * 1024u + (unsigned)tid;
        fx4 z = {0.f, 0.f, 0.f, 0.f};
        __builtin_nontemporal_store(z, base + 0 * 256);
        __builtin_nontemporal_store(z, base + 1 * 256);
        __builtin_nontemporal_store(z, base + 2 * 256);
        __builtin_nontemporal_store(z, base + 3 * 256);
        return;
    }
    ab_body(nodes, W_enc, b_enc, W_cls, b_cls, Axy, Bzw, bid, tid);
}

__global__ __launch_bounds__(256) void fill_edge_kernel(
    const float2* __restrict__ Axy, const float2* __restrict__ Bzw,
    const int* __restrict__ edges,
    float* __restrict__ y, float* __restrict__ yt, int E)
{
    const unsigned g = blockIdx.x * 256u + threadIdx.x;
    if (g < (unsigned)E) {
        const int u = edges[g];
        const int v = edges[E + g];
        if (u < v) {
            const unsigned idx = (((unsigned)u * (16383u - (unsigned)u)) >> 1)
                               + (unsigned)(v - u - 1);
            yt[idx] = 1.0f;
        }
    }
    y_seg(Axy, Bzw, y, g);
}

extern "C" void kernel_launch(void* const* d_in, const int* in_sizes, int n_in,
                              void* d_out, int out_size, void* d_ws, size_t ws_size,
                              hipStream_t stream) {
    const float* nodes = (const float*)d_in[0];
    const int*   edges = (const int*)d_in[1];
    const float* W_enc = (const float*)d_in[2];
    const float* b_enc = (const float*)d_in[3];
    const float* W_cls = (const float*)d_in[4];
    const float* b_cls = (const float*)d_in[5];
    const int E = in_sizes[1] / 2;

    float2*   Axy = (float2*)d_ws;                 // 8192 float2 (64 KB)
    float2*   Bzw = Axy + 8192;                    // 8192 float2 (64 KB)
    unsigned* bm  = (unsigned*)(Bzw + 8192);       // 4.2 MB bitmap

    float* y  = (float*)d_out;                     // [P][2]
    float* yt = (float*)d_out + 2 * PP;            // [P]

    if (ws_size >= 128u * 1024u + NBMW * 4u) {
        // K1: 256 ab blocks + 1024 bitmap-zero blocks
        ab_bmzero_kernel<<<1280, 256, 0, stream>>>(
            nodes, W_enc, b_enc, W_cls, b_cls, Axy, Bzw, bm);
        // K2: edge scatter into bitmap
        scatter_kernel<<<(E + 255) / 256, 256, 0, stream>>>(edges, bm, E);
        // K3: co-scheduled y + yt fill (8191*9 = 73,719 blocks)
        fill_kernel<<<73719, 256, 0, stream>>>(Axy, Bzw, bm, y, yt);
    } else {
        // R10 fallback
        ab_zero_kernel<<<256 + 8191, 256, 0, stream>>>(
            nodes, W_enc, b_enc, W_cls, b_cls, Axy, Bzw, yt);
        fill_edge_kernel<<<(int)(PPU / 512u), 256, 0, stream>>>(
            Axy, Bzw, edges, y, yt, E);
    }
}

// Round 13
// 89.131 us; speedup vs baseline: 1.1159x; 1.1159x over previous
//
#include <hip/hip_runtime.h>

// Problem constants (fixed by the reference file)
#define NN 8192
#define PPU 33550336u              // P = N(N-1)/2
#define NSEG 16775168u             // P/2 (2-pair fx4 segments)
#define SEGLAST 16775167u
static const long long PP = (long long)PPU;

typedef float __attribute__((ext_vector_type(4))) fx4;      // nontemporal-store-able

// skewed LDS index for M float4 rows
#define MSI(j) ((j) + ((j) >> 3))

// ---------------------------------------------------------------------------
// K1: blocks 0..255  -> ab projections (8 threads cooperate per node)
//     blocks 256..8446 -> zero yt (16 KB contiguous per block)
// [byte-identical to the R10 champion]
// ---------------------------------------------------------------------------
__global__ __launch_bounds__(256) void ab_zero_kernel(
    const float* __restrict__ nodes,   // [8192][256]
    const float* __restrict__ W_enc,   // [256][256]
    const float* __restrict__ b_enc,   // [256]
    const float* __restrict__ W_cls,   // [512][2]
    const float* __restrict__ b_cls,   // [2]
    float2* __restrict__ Axy,          // ws: [8192]
    float2* __restrict__ Bzw,          // ws: [8192]
    float*  __restrict__ yt)           // out: [P]
{
    const int tid = threadIdx.x;
    const int bid = blockIdx.x;

    if (bid >= 256) {
        fx4* base = (fx4*)yt + (unsigned)(bid - 256) * 1024u + (unsigned)tid;
        fx4 z = {0.f, 0.f, 0.f, 0.f};
        __builtin_nontemporal_store(z, base + 0 * 256);
        __builtin_nontemporal_store(z, base + 1 * 256);
        __builtin_nontemporal_store(z, base + 2 * 256);
        __builtin_nontemporal_store(z, base + 3 * 256);
        return;
    }

    __shared__ float  wc[1024];        // W_cls [512][2]
    __shared__ float4 msv[288];        // skewed M rows
    __shared__ float  offs[4];

    for (int i = tid; i < 1024; i += 256) wc[i] = W_cls[i];
    __syncthreads();

    {
        const float4* wr  = (const float4*)(W_enc + tid * 256);
        const float4* wa4 = (const float4*)wc;          // A half
        const float4* wb4 = (const float4*)(wc + 512);  // B half
        float a0 = 0.f, a1 = 0.f, a2 = 0.f, a3 = 0.f;
        #pragma unroll 8
        for (int i = 0; i < 64; ++i) {
            const float4 v   = wr[i];
            const float4 A01 = wa4[2*i],   A23 = wa4[2*i+1];
            const float4 B01 = wb4[2*i],   B23 = wb4[2*i+1];
            a0 += v.x*A01.x + v.y*A01.z + v.z*A23.x + v.w*A23.z;
            a1 += v.x*A01.y + v.y*A01.w + v.z*A23.y + v.w*A23.w;
            a2 += v.x*B01.x + v.y*B01.z + v.z*B23.x + v.w*B23.z;
            a3 += v.x*B01.y + v.y*B01.w + v.z*B23.y + v.w*B23.w;
        }
        msv[MSI(tid)] = make_float4(a0, a1, a2, a3);
    }
    if (tid < 4) {
        const int c = tid & 1, base = (tid < 2) ? 0 : 256;
        float o = 0.f;
        for (int j = 0; j < 256; ++j) o += b_enc[j] * wc[(base + j) * 2 + c];
        if (tid < 2) o += b_cls[tid];      // fold b_cls into the A half
        offs[tid] = o;
    }
    __syncthreads();

    const int gid  = bid * 256 + tid;
    const int n    = gid >> 3;             // 0..8191
    const int part = gid & 7;
    float a0 = 0.f, a1 = 0.f, a2 = 0.f, a3 = 0.f;
    const float4* row = (const float4*)(nodes + (long long)n * 256 + part * 32);
    #pragma unroll
    for (int i = 0; i < 8; ++i) {
        const float4 v = row[i];
        const int j = part * 32 + i * 4;
        const float4 m0 = msv[MSI(j+0)];
        const float4 m1 = msv[MSI(j+1)];
        const float4 m2 = msv[MSI(j+2)];
        const float4 m3 = msv[MSI(j+3)];
        a0 += v.x*m0.x + v.y*m1.x + v.z*m2.x + v.w*m3.x;
        a1 += v.x*m0.y + v.y*m1.y + v.z*m2.y + v.w*m3.y;
        a2 += v.x*m0.z + v.y*m1.z + v.z*m2.z + v.w*m3.z;
        a3 += v.x*m0.w + v.y*m1.w + v.z*m2.w + v.w*m3.w;
    }
    #pragma unroll
    for (int d = 1; d < 8; d <<= 1) {
        a0 += __shfl_xor(a0, d);
        a1 += __shfl_xor(a1, d);
        a2 += __shfl_xor(a2, d);
        a3 += __shfl_xor(a3, d);
    }
    if (part == 0) {
        Axy[n] = make_float2(a0 + offs[0], a1 + offs[1]);
        Bzw[n] = make_float2(a2 + offs[2], a3 + offs[3]);
    }
}

// ---------------------------------------------------------------------------
// K2: pipelined looped fill.  2048 blocks; block owns 8192 consecutive
// segments (128 KB y).  Per iter: compute NEXT segment's (s,t) by
// incremental row-walk (no sqrt), issue its 4 loads, combine CURRENT
// (already in registers), NT-store, rotate.  The store never has a
// dependent -> compiler's waitcnt leaves it in flight (no store drain).
// sqrt inversion runs once, in the prologue.  Edge scatter on first 256
// blocks (E = 65536 = 256*256).
// ---------------------------------------------------------------------------
__global__ __launch_bounds__(256) void fill_edge_kernel(
    const float2* __restrict__ Axy,    // [8192]
    const float2* __restrict__ Bzw,    // [8192]
    const int*    __restrict__ edges,  // [2][E]
    float* __restrict__ y,             // [P][2]
    float* __restrict__ yt,            // [P]
    int E)
{
    const int tid = threadIdx.x;
    const unsigned bid = blockIdx.x;

    // edge scatter (first E threads; runs after K1's zero)
    {
        const unsigned ge = bid * 256u + (unsigned)tid;
        if (ge < (unsigned)E) {
            const int u = edges[ge], v = edges[E + ge];
            if (u < v) {
                const unsigned idx = (((unsigned)u * (16383u - (unsigned)u)) >> 1)
                                   + (unsigned)(v - u - 1);
                yt[idx] = 1.0f;
            }
        }
    }

    // prologue: sqrt inversion for this thread's first segment
    unsigned seg = bid * 8192u + (unsigned)tid;
    const unsigned M = 16383u;
    unsigned p = 2u * seg;
    const unsigned disc = M * M - 8u * p;             // exact in uint32
    const float sq = sqrtf((float)disc);
    int s = (int)(((float)M - sq) * 0.5f);
    s = s < 0 ? 0 : (s > NN - 2 ? NN - 2 : s);
    unsigned rs = ((unsigned)s * (M - (unsigned)s)) >> 1;
    while (p < rs)                           { --s; rs -= (unsigned)(NN - 1 - s); }
    while (p >= rs + (unsigned)(NN - 1 - s)) { rs += (unsigned)(NN - 1 - s); ++s; }

    // current segment's operand values
    unsigned t      = p - rs + (unsigned)s + 1u;
    bool     cross  = (t + 1u == (unsigned)NN);       // 2nd pair rolls to next row
    unsigned ia2    = cross ? (unsigned)(s + 1) : (unsigned)s;
    unsigned ib2    = cross ? (unsigned)(s + 2) : t + 1u;
    float2 la  = Axy[s];
    float2 lb  = Bzw[t];
    float2 la2 = Axy[ia2];
    float2 lb2 = Bzw[ib2];

    fx4* yp = (fx4*)y;
    #pragma unroll 2
    for (int it = 0; it < 32; ++it) {
        // ---- next segment indices (incremental; no sqrt) ----
        unsigned segN = seg + 256u;
        segN = segN <= SEGLAST ? segN : SEGLAST;      // tail clamp (idempotent dup)
        const unsigned pN = 2u * segN;
        int sN = s; unsigned rsN = rs;
        while (pN >= rsN + (unsigned)(NN - 1 - sN)) { rsN += (unsigned)(NN - 1 - sN); ++sN; }
        const unsigned tN     = pN - rsN + (unsigned)sN + 1u;
        const bool     crossN = (tN + 1u == (unsigned)NN);
        const unsigned iaN    = crossN ? (unsigned)(sN + 1) : (unsigned)sN;
        const unsigned ibN    = crossN ? (unsigned)(sN + 2) : tN + 1u;

        // ---- issue next loads BEFORE the current store ----
        const float2 laN  = Axy[sN];
        const float2 lbN  = Bzw[tN];
        const float2 la2N = Axy[iaN];
        const float2 lb2N = Bzw[ibN];

        // ---- combine current (register-resident) and store ----
        fx4 v = {la.x + lb.x, la.y + lb.y, la2.x + lb2.x, la2.y + lb2.y};
        __builtin_nontemporal_store(v, yp + seg);

        // ---- rotate ----
        seg = segN; s = sN; rs = rsN;
        la = laN; lb = lbN; la2 = la2N; lb2 = lb2N;
    }
}

extern "C" void kernel_launch(void* const* d_in, const int* in_sizes, int n_in,
                              void* d_out, int out_size, void* d_ws, size_t ws_size,
                              hipStream_t stream) {
    const float* nodes = (const float*)d_in[0];
    const int*   edges = (const int*)d_in[1];
    const float* W_enc = (const float*)d_in[2];
    const float* b_enc = (const float*)d_in[3];
    const float* W_cls = (const float*)d_in[4];
    const float* b_cls = (const float*)d_in[5];
    const int E = in_sizes[1] / 2;

    float2* Axy = (float2*)d_ws;                  // 8192 float2
    float2* Bzw = Axy + 8192;                     // 8192 float2

    float* y  = (float*)d_out;                    // [P][2]
    float* yt = (float*)d_out + 2 * PP;           // [P]

    // K1: 256 ab blocks + 8191 zero blocks (P floats = 8191*1024 fx4 exactly)
    ab_zero_kernel<<<256 + 8191, 256, 0, stream>>>(
        nodes, W_enc, b_enc, W_cls, b_cls, Axy, Bzw, yt);

    // K2: 2048 blocks * 256 threads * 32 iters covers NSEG segments (clamped tail)
    fill_edge_kernel<<<2048, 256, 0, stream>>>(Axy, Bzw, edges, y, yt, E);
}